// Round 9
// baseline (4427.954 us; speedup 1.0000x reference)
//
#include <hip/hip_runtime.h>
#include <cstdio>
#include <math.h>

typedef unsigned short u16;
typedef float f32x4 __attribute__((ext_vector_type(4)));
typedef __bf16 bf16x8 __attribute__((ext_vector_type(8)));
typedef u16 u16x4 __attribute__((ext_vector_type(4)));
typedef u16 u16x8 __attribute__((ext_vector_type(8)));

__device__ __forceinline__ u16 f2bf(float x) {
  unsigned u = __float_as_uint(x);
  u = (u + 0x7FFFu + ((u >> 16) & 1u)) >> 16;
  return (u16)u;
}
__device__ __forceinline__ float bf2f(u16 x) {
  return __uint_as_float(((unsigned)x) << 16);
}

__device__ __forceinline__ f32x4 mfma_bf16(bf16x8 a, bf16x8 b, f32x4 c) {
  return __builtin_amdgcn_mfma_f32_16x16x32_bf16(a, b, c, 0, 0, 0);
}

// async global->LDS, 16B per lane. LDS dest = wave-uniform base + lane*16.
__device__ __forceinline__ void gload_lds16(const void* g, void* l) {
  __builtin_amdgcn_global_load_lds(
      (const __attribute__((address_space(1))) void*)g,
      (__attribute__((address_space(3))) void*)l, 16, 0, 0);
}

// C[m,n] = scale * sum_k A[m,k] * B[n,k]   (both operands K-contiguous)
// BM=256 x BN=256, BK=32. 512 threads = 8 waves (2M x 4N), per-wave 128x64 out.
// DOUBLE-buffered LDS, 32KB/buf, 64KB total -> 2 BLOCKS/CU RESIDENT (r9 change:
// r7/r8's 128KB quad-buffer forced 1 block/CU; every wait idled the whole CU.
// With 2 blocks, the co-resident block's MFMA/loads overlap our drain, m114).
// Per tile: STAGE(t+1 -> buf^1) issued first (load->use ~1 tile), ds_read+MFMA
// on buf, __syncthreads() (vmcnt0+lgkm drain + barrier; drain overlaps other
// block). Race-free: buf^1's last reads finished before the previous barrier.
// Rows are 64B (4 x 16B slots): XOR-swizzle slot ^= (row>>1)&3, applied via
// pre-swizzled global SOURCE (linear gload dest) + swizzled read addr (T2).
// Block-index modes:
//  SWZ: chunked XCD swizzle on flattened (x,y,z) id (identity unless nwg%8==0):
//       each XCD gets a contiguous logical run -> L2 working set = one batch
//       (r8 lesson: TRI/PV interleaved all batches per XCD -> 2.3x overfetch).
//  TRI: compact causal grid: gridDim.x == 36 == live tiles of the 8x8 256x256
//       triangular tiling (bx <= by), z = f / 36. Equal-work tiles.
//  SWAPXY: decoded x -> m-block, y -> n-block (PV: o on x, t on y; with SWZ
//       each XCD gets whole batches -> KLIMIT work balanced per XCD).
template <bool BF16OUT, bool SWZ, bool TRI, bool KLIMIT, bool SWAPXY>
__global__ __launch_bounds__(512, 4) void gemm_bt(
    const u16* __restrict__ A, const u16* __restrict__ B, void* __restrict__ Cv,
    int K, int lda, int ldb, int ldc,
    long long sAz, long long sBz, long long sCz, float scale)
{
  int bx, by, z;
  {
    const int gx = gridDim.x, gy = gridDim.y;
    const int nwg = gx * gy * gridDim.z;
    int f = blockIdx.x + gx * (blockIdx.y + gy * blockIdx.z);
    if (SWZ && (nwg & 7) == 0) f = (f & 7) * (nwg >> 3) + (f >> 3);
    if (TRI) {
      const int j = f % gx;  // gx == 36
      z = f / gx;
      int r = (int)((sqrtf(8.f * j + 1.f) - 1.f) * 0.5f);
      while (r * (r + 1) / 2 > j) --r;
      while ((r + 1) * (r + 2) / 2 <= j) ++r;
      by = r;
      bx = j - r * (r + 1) / 2;
    } else {
      const int x = f % gx;
      const int rest = f / gx;
      const int y = rest % gy;
      z = rest / gy;
      if (SWAPXY) { bx = y; by = x; } else { bx = x; by = y; }
    }
  }

  const int n0 = bx * 256;
  const int m0 = by * 256;
  A += (long long)z * sAz;
  B += (long long)z * sBz;

  const int tid = threadIdx.x;
  const int wave = tid >> 6, lane = tid & 63;
  const int wr = wave >> 2, wc = wave & 3;  // 2M x 4N wave grid

  // per buffer: A [256][32] u16 at 0..8191, B [256][32] u16 at 8192..16383
  __shared__ u16 lds[2][16384];

  f32x4 acc[8][4] = {};

  int kEnd = K;
  if (KLIMIT) { int ke = n0 + 256; kEnd = ke < K ? ke : K; }  // P[t,s]==0 for s>t
  const int nt = kEnd >> 5;

  // ---- staging: one gload call = 512 lanes x 16B = 128 rows of 64B.
  // lane l (in wave w, call c): row = c*128 + w*16 + (l>>2), phys slot = l&3.
  // logical slot = phys ^ ((row>>1)&3) = (l&3) ^ ((l>>3)&3)  [c*128, w*16 = 0 mod 8]
  const int sOff = ((lane & 3) ^ ((lane >> 3) & 3)) * 8;  // element offset in row
  const u16* gAs = A + (long long)(m0 + wave * 16 + (lane >> 2)) * lda + sOff;
  const u16* gBs = B + (long long)(n0 + wave * 16 + (lane >> 2)) * ldb + sOff;

  // ---- read: logical slot g lives at phys slot g ^ ((row>>1)&3); for rows
  // (base + m*16 + frow) with base,m*16 = 0 mod 8: (row>>1)&3 == (frow>>1)&3.
  const int frow = lane & 15, g = lane >> 4;
  const int ps = g ^ ((frow >> 1) & 3);
  const int aBase = (wr * 128 + frow) * 32 + ps * 8;          // + m*512
  const int bBase = 8192 + (wc * 64 + frow) * 32 + ps * 8;    // + n*512

#define STAGE_A(T, BUF)                                                        \
  {                                                                            \
    const long long kc = (long long)(T) * 32;                                  \
    _Pragma("unroll")                                                          \
    for (int c = 0; c < 2; ++c)                                                \
      gload_lds16(gAs + (long long)(c * 128) * lda + kc,                       \
                  &lds[BUF][c * 4096 + wave * 512]);                           \
  }
#define STAGE_B(T, BUF)                                                        \
  {                                                                            \
    const long long kc = (long long)(T) * 32;                                  \
    _Pragma("unroll")                                                          \
    for (int c = 0; c < 2; ++c)                                                \
      gload_lds16(gBs + (long long)(c * 128) * ldb + kc,                       \
                  &lds[BUF][8192 + c * 4096 + wave * 512]);                    \
  }

  // ---- prologue: stage t0 -> buf0; syncthreads drains vmcnt before reads
  STAGE_A(0, 0) STAGE_B(0, 0)
  __syncthreads();

  for (int t = 0; t < nt; ++t) {
    const u16* bb = &lds[t & 1][0];

    // issue next tile's stage first: target buffer's last reads completed
    // before the barrier we just crossed; maximizes load->use distance.
    if (t + 1 < nt) { STAGE_A(t + 1, (t + 1) & 1) STAGE_B(t + 1, (t + 1) & 1) }

    bf16x8 af[4], a2[4], bf[4];
#pragma unroll
    for (int m = 0; m < 4; ++m) af[m] = *(const bf16x8*)(bb + aBase + m * 512);
#pragma unroll
    for (int n = 0; n < 4; ++n) bf[n] = *(const bf16x8*)(bb + bBase + n * 512);
#pragma unroll
    for (int m = 0; m < 4; ++m) a2[m] = *(const bf16x8*)(bb + aBase + (4 + m) * 512);

    __builtin_amdgcn_s_setprio(1);
#pragma unroll
    for (int m = 0; m < 4; ++m)
#pragma unroll
      for (int n = 0; n < 4; ++n)
        acc[m][n] = mfma_bf16(af[m], bf[n], acc[m][n]);
#pragma unroll
    for (int m = 0; m < 4; ++m)
#pragma unroll
      for (int n = 0; n < 4; ++n)
        acc[4 + m][n] = mfma_bf16(a2[m], bf[n], acc[4 + m][n]);
    __builtin_amdgcn_s_setprio(0);

    // vmcnt(0)+lgkm drain + barrier; drain overlaps the co-resident block.
    __syncthreads();
  }
#undef STAGE_A
#undef STAGE_B

  // C/D layout: col = lane&15, row = (lane>>4)*4 + r  [m89-verified]
  const int crow0 = m0 + wr * 128 + (lane >> 4) * 4;
  const int ccol0 = n0 + wc * 64 + (lane & 15);
  if (BF16OUT) {
    u16* C = (u16*)Cv + (long long)z * sCz;
#pragma unroll
    for (int m = 0; m < 8; ++m)
#pragma unroll
      for (int n = 0; n < 4; ++n)
#pragma unroll
        for (int r = 0; r < 4; ++r)
          C[(long long)(crow0 + m * 16 + r) * ldc + ccol0 + n * 16] = f2bf(acc[m][n][r] * scale);
  } else {
    float* C = (float*)Cv + (long long)z * sCz;
#pragma unroll
    for (int m = 0; m < 8; ++m)
#pragma unroll
      for (int n = 0; n < 4; ++n)
#pragma unroll
        for (int r = 0; r < 4; ++r)
          C[(long long)(crow0 + m * 16 + r) * ldc + ccol0 + n * 16] = acc[m][n][r] * scale;
  }
}

// (b, i, s) fp32  ->  (b, s, i) bf16 ; one 64x64 tile per block, block (64,4)
__global__ __launch_bounds__(256) void conv_transpose(const float* __restrict__ src, u16* __restrict__ dst)
{
  const int b = blockIdx.z;
  const float* s = src + (long long)b * 1024 * 2048;
  u16* d = dst + (long long)b * 2048 * 1024;
  const int s0 = blockIdx.x * 64, i0 = blockIdx.y * 64;
  const int tx = threadIdx.x, ty = threadIdx.y;
  __shared__ float tile[64][65];
#pragma unroll
  for (int r = 0; r < 16; ++r)
    tile[r * 4 + ty][tx] = s[(long long)(i0 + r * 4 + ty) * 2048 + s0 + tx];
  __syncthreads();
#pragma unroll
  for (int r = 0; r < 16; ++r)
    d[(long long)(s0 + r * 4 + ty) * 1024 + i0 + tx] = f2bf(tile[tx][r * 4 + ty]);
}

__global__ __launch_bounds__(256) void conv_weights(
    const float* __restrict__ a, const float* __restrict__ b, const float* __restrict__ c,
    u16* __restrict__ oa, u16* __restrict__ ob, u16* __restrict__ oc)
{
  const int which = blockIdx.y;
  const float* s = which == 0 ? a : which == 1 ? b : c;
  u16* d = which == 0 ? oa : which == 1 ? ob : oc;
  const int idx = (blockIdx.x * 256 + threadIdx.x) * 4;
  f32x4 v = *(const f32x4*)(s + idx);
  u16x4 o;
#pragma unroll
  for (int j = 0; j < 4; ++j) o[j] = f2bf(v[j]);
  *(u16x4*)(d + idx) = o;
}

// Row t of S'[t,s] (bf16 in): mask by index (s<=t), max, sum-exp, write P bf16.
// One row per block; 256 threads x 8 elems = 2048.
__global__ __launch_bounds__(256) void col_softmax(const u16* __restrict__ S, u16* __restrict__ P)
{
  const int t = blockIdx.x;
  const long long rowOff = ((long long)blockIdx.y * 2048 + t) * 2048;
  const u16* row = S + rowOff;
  u16* prow = P + rowOff;
  const int tid = threadIdx.x;
  const int i0 = tid * 8;

  u16x8 a = *(const u16x8*)(row + i0);
  float v[8];
#pragma unroll
  for (int j = 0; j < 8; ++j)
    v[j] = (i0 + j <= t) ? bf2f(a[j]) : -1e30f;  // unwritten/masked discarded by index

  float m = v[0];
#pragma unroll
  for (int j = 1; j < 8; ++j) m = fmaxf(m, v[j]);
#pragma unroll
  for (int off = 32; off; off >>= 1) m = fmaxf(m, __shfl_xor(m, off));
  __shared__ float red[4];
  __shared__ float red2[4];
  if ((tid & 63) == 0) red[tid >> 6] = m;
  __syncthreads();
  m = fmaxf(fmaxf(red[0], red[1]), fmaxf(red[2], red[3]));

  float e[8]; float ssum = 0.f;
#pragma unroll
  for (int j = 0; j < 8; ++j) { e[j] = __expf(v[j] - m); ssum += e[j]; }
#pragma unroll
  for (int off = 32; off; off >>= 1) ssum += __shfl_xor(ssum, off);
  if ((tid & 63) == 0) red2[tid >> 6] = ssum;
  __syncthreads();
  ssum = red2[0] + red2[1] + red2[2] + red2[3];
  const float inv = 1.0f / ssum;
  u16x8 o;
#pragma unroll
  for (int j = 0; j < 8; ++j) o[j] = f2bf(e[j] * inv);
  *(u16x8*)(prow + i0) = o;
}

extern "C" void kernel_launch(void* const* d_in, const int* in_sizes, int n_in,
                              void* d_out, int out_size, void* d_ws, size_t ws_size,
                              hipStream_t stream)
{
  const float* Q  = (const float*)d_in[0];
  const float* K  = (const float*)d_in[1];
  const float* V  = (const float*)d_in[2];
  const float* WQ = (const float*)d_in[3];
  const float* WK = (const float*)d_in[4];
  const float* WV = (const float*)d_in[5];
  float* out = (float*)d_out;

  const size_t MB = 1ull << 20;
  char* w = (char*)d_ws;
  if (ws_size < 262 * MB) {
    fprintf(stderr, "kernel_launch: workspace too small (%zu B, need >= %zu B)\n",
            ws_size, (size_t)(262 * MB));
    return;
  }

  // ws layout (MB): [0,6) weights bf16 | [6,70) Qd_t | [70,134) Kd_t | [134,198) Vd
  // [198, ...) transient: transposed-input buffer (64MB), later S(bf16)+P(bf16) chunks
  u16* wq    = (u16*)(w + 0 * MB);
  u16* wk    = (u16*)(w + 2 * MB);
  u16* wv    = (u16*)(w + 4 * MB);
  u16* qdt   = (u16*)(w + 6 * MB);
  u16* kdt   = (u16*)(w + 70 * MB);
  u16* vd    = (u16*)(w + 134 * MB);
  u16* trans = (u16*)(w + 198 * MB);
  u16* S     = (u16*)(w + 198 * MB);

  long long freeMB = (long long)(ws_size / MB) - 198;
  int chunk = (int)(freeMB / 16);  // 8MB S + 8MB P per batch (both bf16)
  if (chunk > 8) chunk = 8;
  u16* P = (u16*)(w + (198 + (size_t)chunk * 8) * MB);

  conv_weights<<<dim3(1024, 3), 256, 0, stream>>>(WQ, WK, WV, wq, wk, wv);

  // Projections. Qd_t/Kd_t stored (b, seq, o) = one (32768 x 1024) GEMM each;
  // Vd stored (b, o, seq), per-batch z.
  conv_transpose<<<dim3(32, 16, 16), dim3(64, 4), 0, stream>>>(Q, trans);
  gemm_bt<true, true, false, false, false><<<dim3(4, 128, 1), 512, 0, stream>>>(
      trans, wq, qdt, 1024, 1024, 1024, 1024, 0, 0, 0, 1.0f);
  conv_transpose<<<dim3(32, 16, 16), dim3(64, 4), 0, stream>>>(K, trans);
  gemm_bt<true, true, false, false, false><<<dim3(4, 128, 1), 512, 0, stream>>>(
      trans, wk, kdt, 1024, 1024, 1024, 1024, 0, 0, 0, 1.0f);
  conv_transpose<<<dim3(32, 16, 16), dim3(64, 4), 0, stream>>>(V, trans);
  gemm_bt<true, true, false, false, false><<<dim3(8, 4, 16), 512, 0, stream>>>(
      wv, trans, vd, 1024, 1024, 1024, 2048,
      0, (long long)2048 * 1024, (long long)1024 * 2048, 1.0f);

  // Attention per batch-chunk:
  //  S'[t,s] = Kd_t[t,:]·Qd_t[s,:]/32 — compact triangular grid (36 live tiles/z),
  //  chunked swizzle -> one batch per XCD (Kd+Qd ws ~8MB, panel-sequential)
  //  row-softmax over s (masked by index), S/P bf16
  //  out[o,t] = sum_s Vd[o,s] P[t,s] — KLIMIT; chunked swizzle gives each XCD
  //  whole batches -> per-XCD KLIMIT work equal; Vd(z)+P(z) L2-resident.
  for (int b0 = 0; b0 < 16; b0 += chunk) {
    const int nb = (16 - b0) < chunk ? (16 - b0) : chunk;
    gemm_bt<true, true, true, false, false><<<dim3(36, 1, nb), 512, 0, stream>>>(
        kdt + (long long)b0 * 2048 * 1024, qdt + (long long)b0 * 2048 * 1024, S,
        1024, 1024, 1024, 2048,
        (long long)2048 * 1024, (long long)2048 * 1024, (long long)2048 * 2048, 0.03125f);
    col_softmax<<<dim3(2048, nb), 256, 0, stream>>>(S, P);
    gemm_bt<false, true, false, true, true><<<dim3(4, 8, nb), 512, 0, stream>>>(
        vd + (long long)b0 * 1024 * 2048, P, out + (long long)b0 * 1024 * 2048,
        2048, 2048, 2048, 2048,
        (long long)1024 * 2048, (long long)2048 * 2048, (long long)1024 * 2048, 1.0f);
  }
}

// Round 10
// 640.475 us; speedup vs baseline: 6.9135x; 6.9135x over previous
//
#include <hip/hip_runtime.h>
#include <cstdio>
#include <math.h>

typedef unsigned short u16;
typedef float f32x4 __attribute__((ext_vector_type(4)));
typedef __bf16 bf16x8 __attribute__((ext_vector_type(8)));
typedef u16 u16x4 __attribute__((ext_vector_type(4)));
typedef u16 u16x8 __attribute__((ext_vector_type(8)));

__device__ __forceinline__ u16 f2bf(float x) {
  unsigned u = __float_as_uint(x);
  u = (u + 0x7FFFu + ((u >> 16) & 1u)) >> 16;
  return (u16)u;
}
__device__ __forceinline__ float bf2f(u16 x) {
  return __uint_as_float(((unsigned)x) << 16);
}

__device__ __forceinline__ f32x4 mfma_bf16(bf16x8 a, bf16x8 b, f32x4 c) {
  return __builtin_amdgcn_mfma_f32_16x16x32_bf16(a, b, c, 0, 0, 0);
}

// async global->LDS, 16B per lane. LDS dest = wave-uniform base + lane*16.
__device__ __forceinline__ void gload_lds16(const void* g, void* l) {
  __builtin_amdgcn_global_load_lds(
      (const __attribute__((address_space(1))) void*)g,
      (__attribute__((address_space(3))) void*)l, 16, 0, 0);
}

// C[m,n] = scale * sum_k A[m,k] * B[n,k]   (both operands K-contiguous)
// BM=BN=256, BK=64. 512 threads = 8 waves (2M x 4N), per-wave 128x64 out.
// m201-style 8-phase-per-2-K-tiles schedule (here: 4 phases per K-64 tile):
// each phase = {ds-read quadrant frags; stage 1 half-tile (2 gloads);
//   s_barrier; lgkmcnt(0)+sched_barrier(0) [rule #18]; setprio(1); 16 MFMA;
//   setprio(0); [counted vmcnt]; s_barrier}.
// LDS 128KB: 2 buffers x {A 32KB + B 32KB}; double-buffered (1 block/CU —
// r9 lesson: acc=128 regs forces 256-reg tier, 2 blocks/CU impossible; the
// win must come from within-block pipelining, launch_bounds(512,2) ONLY).
// B stored as two n-pair-remapped halves: B-lo' = rows {wc*64+0..31, all wc}
// (the n0-1 frags of every wave), B-hi' = the n2-3 rows. Stage order per tile
// t (for t+1): ph1 A-lo, ph2 A-hi, ph3 B-lo', ph4 B-hi'. Waits (before a
// barrier; reads of validated region follow it -> cross-wave DMA safe):
//   end-ph1: vmcnt(2) retires B-hi'(t) (read in ph2)
//   end-ph4: vmcnt(2) retires A-lo,A-hi,B-lo'(t+1) (read in ph1)
// Never vmcnt(0) mid-loop (T4). Min lead ~2 phases (~1000cy > 900cy HBM).
// Rows = 128B = 8 x 16B slots: XOR-swizzle slot ^= row&7 via pre-swizzled
// global SOURCE (linear gload dest) + swizzled ds_read addr (T2).
// Requires nt >= 2 (K >= 128), M%256==0, N%256==0, K%64==0.
// Block-index modes:
//  SWZ: chunked XCD swizzle on flattened (x,y,z) id (identity unless nwg%8==0).
//  TRI: compact causal grid: gridDim.x == 36 live tiles of 8x8 triangular
//       tiling (bx <= by), z = f/36. Equal-work tiles round-robin balanced.
//  SWAPXY: decoded x -> m-block, y -> n-block (PV balance).
template <bool BF16OUT, bool SWZ, bool TRI, bool KLIMIT, bool SWAPXY>
__global__ __launch_bounds__(512, 2) void gemm_bt(
    const u16* __restrict__ A, const u16* __restrict__ B, void* __restrict__ Cv,
    int K, int lda, int ldb, int ldc,
    long long sAz, long long sBz, long long sCz, float scale)
{
  int bx, by, z;
  {
    const int gx = gridDim.x, gy = gridDim.y;
    const int nwg = gx * gy * gridDim.z;
    int f = blockIdx.x + gx * (blockIdx.y + gy * blockIdx.z);
    if (SWZ && (nwg & 7) == 0) f = (f & 7) * (nwg >> 3) + (f >> 3);
    if (TRI) {
      const int j = f % gx;  // gx == 36
      z = f / gx;
      int r = (int)((sqrtf(8.f * j + 1.f) - 1.f) * 0.5f);
      while (r * (r + 1) / 2 > j) --r;
      while ((r + 1) * (r + 2) / 2 <= j) ++r;
      by = r;
      bx = j - r * (r + 1) / 2;
    } else {
      const int x = f % gx;
      const int rest = f / gx;
      const int y = rest % gy;
      z = rest / gy;
      if (SWAPXY) { bx = y; by = x; } else { bx = x; by = y; }
    }
  }

  const int n0 = bx * 256;
  const int m0 = by * 256;
  A += (long long)z * sAz;
  B += (long long)z * sBz;

  const int tid = threadIdx.x;
  const int wave = tid >> 6, lane = tid & 63;
  const int wr = wave >> 2, wc = wave & 3;  // 2M x 4N wave grid

  // per buffer (32768 u16): A [256][64] at 0..16383; B' halves at 16384 +
  // half*8192 + r'[0..127]*64.
  __shared__ u16 lds[2][32768];

  f32x4 acc[8][4] = {};

  int kEnd = K;
  if (KLIMIT) { int ke = n0 + 256; kEnd = ke < K ? ke : K; }  // P[t,s]==0 for s>t
  const int nt = kEnd >> 6;  // >= 4 for all our launches

  // ---- staging: one gload call = 512 lanes x 16B = 64 rows of 128B.
  // lane l of wave w: row-in-call = w*8 + (l>>3), phys slot = l&7.
  // pre-swizzled source: logical slot = phys ^ (row&7); row&7 == (l>>3)&7.
  const int sOff = ((lane & 7) ^ ((lane >> 3) & 7)) * 8;  // elem offset in row
  const int r0 = wave * 8 + (lane >> 3);                  // row within call
  const u16* gA0 = A + (long long)(m0 + r0) * lda + sOff; // + c*64*lda + k
  // B call c (c0,1 = B-lo', c2,3 = B-hi'): r' = (c&1)*64 + r0;
  // actual row = (r'>>5)*64 + (c>>1)*32 + (r'&31). (r'&7 == r0&7 -> sOff ok)

  // ---- read: logical (row, slot s) at phys slot s^(row&7); frag rows have
  // row&7 == frow&7 (all bases = 0 mod 8... wc*32,(n&1)*16,m*16,wr*128).
  const int frow = lane & 15, g = lane >> 4, swz = frow & 7;

#define AOFF(m, kk) ((wr * 128 + (m) * 16 + frow) * 64 + ((((kk) * 4 + g)) ^ swz) * 8)
#define BOFF(n, kk) (16384 + ((n) >> 1) * 8192 + (wc * 32 + ((n) & 1) * 16 + frow) * 64 + (((kk) * 4 + g) ^ swz) * 8)

#define STAGE_A(T, BUF, H)                                                     \
  {                                                                            \
    const long long kc = (long long)(T) * 64;                                  \
    _Pragma("unroll")                                                          \
    for (int c = (H) * 2; c < (H) * 2 + 2; ++c)                                \
      gload_lds16(gA0 + (long long)(c * 64) * lda + kc,                        \
                  &lds[BUF][c * 4096 + wave * 512]);                           \
  }
#define STAGE_B(T, BUF, H)                                                     \
  {                                                                            \
    const long long kc = (long long)(T) * 64;                                  \
    _Pragma("unroll")                                                          \
    for (int c = (H) * 2; c < (H) * 2 + 2; ++c) {                              \
      const int rp = (c & 1) * 64 + r0;                                        \
      const int row = (rp >> 5) * 64 + (c >> 1) * 32 + (rp & 31);              \
      gload_lds16(B + (long long)(n0 + row) * ldb + sOff + kc,                 \
                  &lds[BUF][16384 + c * 4096 + wave * 512]);                   \
    }                                                                          \
  }

  bf16x8 pA[8], pB[4];
#define READ_A(mb)                                                             \
  _Pragma("unroll")                                                            \
  for (int i = 0; i < 4; ++i) {                                                \
    pA[i * 2 + 0] = *(const bf16x8*)(bb + AOFF((mb) + i, 0));                  \
    pA[i * 2 + 1] = *(const bf16x8*)(bb + AOFF((mb) + i, 1));                  \
  }
#define READ_B(nb)                                                             \
  _Pragma("unroll")                                                            \
  for (int i = 0; i < 2; ++i) {                                                \
    pB[i * 2 + 0] = *(const bf16x8*)(bb + BOFF((nb) + i, 0));                  \
    pB[i * 2 + 1] = *(const bf16x8*)(bb + BOFF((nb) + i, 1));                  \
  }
#define MFMA16(mb, nb)                                                         \
  _Pragma("unroll")                                                            \
  for (int i = 0; i < 4; ++i)                                                  \
    _Pragma("unroll")                                                          \
    for (int j = 0; j < 2; ++j) {                                              \
      acc[(mb) + i][(nb) + j] =                                                \
          mfma_bf16(pA[i * 2 + 0], pB[j * 2 + 0], acc[(mb) + i][(nb) + j]);    \
      acc[(mb) + i][(nb) + j] =                                                \
          mfma_bf16(pA[i * 2 + 1], pB[j * 2 + 1], acc[(mb) + i][(nb) + j]);    \
    }

#define BAR()  __builtin_amdgcn_s_barrier()
#define LGKM0()                                                                \
  asm volatile("s_waitcnt lgkmcnt(0)" ::: "memory");                           \
  __builtin_amdgcn_sched_barrier(0)
#define VM(N) asm volatile("s_waitcnt vmcnt(" #N ")" ::: "memory")

  // ---- prologue: stage tile0 (A-lo, A-hi, B-lo', B-hi' = 8 loads FIFO);
  // vmcnt(2) retires all but B-hi' (first read in ph2, revalidated end-ph1).
  STAGE_A(0, 0, 0) STAGE_A(0, 0, 1) STAGE_B(0, 0, 0) STAGE_B(0, 0, 1)
  VM(2);
  BAR();

  for (int t = 0; t < nt; ++t) {
    const u16* bb = &lds[t & 1][0];
    const int nxb = (t + 1) & 1;
    const bool pf = (t + 1 < nt);

    // ph1: read A m0-3 + B n0-1; stage A-lo(t+1); MFMA m0-3 x n0-1
    READ_A(0) READ_B(0)
    if (pf) STAGE_A(t + 1, nxb, 0)
    BAR(); LGKM0();
    __builtin_amdgcn_s_setprio(1); MFMA16(0, 0); __builtin_amdgcn_s_setprio(0);
    if (pf) VM(2); else VM(0);   // retire B-hi'(t) before ph2 reads it
    BAR();

    // ph2: read B n2-3 (A regs reused); stage A-hi(t+1); MFMA m0-3 x n2-3
    READ_B(2)
    if (pf) STAGE_A(t + 1, nxb, 1)
    BAR(); LGKM0();
    __builtin_amdgcn_s_setprio(1); MFMA16(0, 2); __builtin_amdgcn_s_setprio(0);
    BAR();

    // ph3: read A m4-7 (B regs reused); stage B-lo'(t+1); MFMA m4-7 x n2-3
    READ_A(4)
    if (pf) STAGE_B(t + 1, nxb, 0)
    BAR(); LGKM0();
    __builtin_amdgcn_s_setprio(1); MFMA16(4, 2); __builtin_amdgcn_s_setprio(0);
    BAR();

    // ph4: read B n0-1; stage B-hi'(t+1); MFMA m4-7 x n0-1
    READ_B(0)
    if (pf) STAGE_B(t + 1, nxb, 1)
    BAR(); LGKM0();
    __builtin_amdgcn_s_setprio(1); MFMA16(4, 0); __builtin_amdgcn_s_setprio(0);
    if (pf) VM(2); else VM(0);   // retire A-lo,A-hi,B-lo'(t+1) for ph1
    BAR();
  }
#undef STAGE_A
#undef STAGE_B
#undef READ_A
#undef READ_B
#undef MFMA16
#undef AOFF
#undef BOFF
#undef BAR
#undef LGKM0
#undef VM

  // C/D layout: col = lane&15, row = (lane>>4)*4 + r  [m89-verified]
  const int crow0 = m0 + wr * 128 + (lane >> 4) * 4;
  const int ccol0 = n0 + wc * 64 + (lane & 15);
  if (BF16OUT) {
    u16* C = (u16*)Cv + (long long)z * sCz;
#pragma unroll
    for (int m = 0; m < 8; ++m)
#pragma unroll
      for (int n = 0; n < 4; ++n)
#pragma unroll
        for (int r = 0; r < 4; ++r)
          C[(long long)(crow0 + m * 16 + r) * ldc + ccol0 + n * 16] = f2bf(acc[m][n][r] * scale);
  } else {
    float* C = (float*)Cv + (long long)z * sCz;
#pragma unroll
    for (int m = 0; m < 8; ++m)
#pragma unroll
      for (int n = 0; n < 4; ++n)
#pragma unroll
        for (int r = 0; r < 4; ++r)
          C[(long long)(crow0 + m * 16 + r) * ldc + ccol0 + n * 16] = acc[m][n][r] * scale;
  }
}

// (b, i, s) fp32  ->  (b, s, i) bf16 ; one 64x64 tile per block, block (64,4)
__global__ __launch_bounds__(256) void conv_transpose(const float* __restrict__ src, u16* __restrict__ dst)
{
  const int b = blockIdx.z;
  const float* s = src + (long long)b * 1024 * 2048;
  u16* d = dst + (long long)b * 2048 * 1024;
  const int s0 = blockIdx.x * 64, i0 = blockIdx.y * 64;
  const int tx = threadIdx.x, ty = threadIdx.y;
  __shared__ float tile[64][65];
#pragma unroll
  for (int r = 0; r < 16; ++r)
    tile[r * 4 + ty][tx] = s[(long long)(i0 + r * 4 + ty) * 2048 + s0 + tx];
  __syncthreads();
#pragma unroll
  for (int r = 0; r < 16; ++r)
    d[(long long)(s0 + r * 4 + ty) * 1024 + i0 + tx] = f2bf(tile[tx][r * 4 + ty]);
}

__global__ __launch_bounds__(256) void conv_weights(
    const float* __restrict__ a, const float* __restrict__ b, const float* __restrict__ c,
    u16* __restrict__ oa, u16* __restrict__ ob, u16* __restrict__ oc)
{
  const int which = blockIdx.y;
  const float* s = which == 0 ? a : which == 1 ? b : c;
  u16* d = which == 0 ? oa : which == 1 ? ob : oc;
  const int idx = (blockIdx.x * 256 + threadIdx.x) * 4;
  f32x4 v = *(const f32x4*)(s + idx);
  u16x4 o;
#pragma unroll
  for (int j = 0; j < 4; ++j) o[j] = f2bf(v[j]);
  *(u16x4*)(d + idx) = o;
}

// Row t of S'[t,s] (bf16 in): mask by index (s<=t), max, sum-exp, write P bf16.
// One row per block; 256 threads x 8 elems = 2048.
__global__ __launch_bounds__(256) void col_softmax(const u16* __restrict__ S, u16* __restrict__ P)
{
  const int t = blockIdx.x;
  const long long rowOff = ((long long)blockIdx.y * 2048 + t) * 2048;
  const u16* row = S + rowOff;
  u16* prow = P + rowOff;
  const int tid = threadIdx.x;
  const int i0 = tid * 8;

  u16x8 a = *(const u16x8*)(row + i0);
  float v[8];
#pragma unroll
  for (int j = 0; j < 8; ++j)
    v[j] = (i0 + j <= t) ? bf2f(a[j]) : -1e30f;  // unwritten/masked discarded by index

  float m = v[0];
#pragma unroll
  for (int j = 1; j < 8; ++j) m = fmaxf(m, v[j]);
#pragma unroll
  for (int off = 32; off; off >>= 1) m = fmaxf(m, __shfl_xor(m, off));
  __shared__ float red[4];
  __shared__ float red2[4];
  if ((tid & 63) == 0) red[tid >> 6] = m;
  __syncthreads();
  m = fmaxf(fmaxf(red[0], red[1]), fmaxf(red[2], red[3]));

  float e[8]; float ssum = 0.f;
#pragma unroll
  for (int j = 0; j < 8; ++j) { e[j] = __expf(v[j] - m); ssum += e[j]; }
#pragma unroll
  for (int off = 32; off; off >>= 1) ssum += __shfl_xor(ssum, off);
  if ((tid & 63) == 0) red2[tid >> 6] = ssum;
  __syncthreads();
  ssum = red2[0] + red2[1] + red2[2] + red2[3];
  const float inv = 1.0f / ssum;
  u16x8 o;
#pragma unroll
  for (int j = 0; j < 8; ++j) o[j] = f2bf(e[j] * inv);
  *(u16x8*)(prow + i0) = o;
}

extern "C" void kernel_launch(void* const* d_in, const int* in_sizes, int n_in,
                              void* d_out, int out_size, void* d_ws, size_t ws_size,
                              hipStream_t stream)
{
  const float* Q  = (const float*)d_in[0];
  const float* K  = (const float*)d_in[1];
  const float* V  = (const float*)d_in[2];
  const float* WQ = (const float*)d_in[3];
  const float* WK = (const float*)d_in[4];
  const float* WV = (const float*)d_in[5];
  float* out = (float*)d_out;

  const size_t MB = 1ull << 20;
  char* w = (char*)d_ws;
  if (ws_size < 262 * MB) {
    fprintf(stderr, "kernel_launch: workspace too small (%zu B, need >= %zu B)\n",
            ws_size, (size_t)(262 * MB));
    return;
  }

  // ws layout (MB): [0,6) weights bf16 | [6,70) Qd_t | [70,134) Kd_t | [134,198) Vd
  // [198, ...) transient: transposed-input buffer (64MB), later S(bf16)+P(bf16) chunks
  u16* wq    = (u16*)(w + 0 * MB);
  u16* wk    = (u16*)(w + 2 * MB);
  u16* wv    = (u16*)(w + 4 * MB);
  u16* qdt   = (u16*)(w + 6 * MB);
  u16* kdt   = (u16*)(w + 70 * MB);
  u16* vd    = (u16*)(w + 134 * MB);
  u16* trans = (u16*)(w + 198 * MB);
  u16* S     = (u16*)(w + 198 * MB);

  long long freeMB = (long long)(ws_size / MB) - 198;
  int chunk = (int)(freeMB / 16);  // 8MB S + 8MB P per batch (both bf16)
  if (chunk > 8) chunk = 8;
  u16* P = (u16*)(w + (198 + (size_t)chunk * 8) * MB);

  conv_weights<<<dim3(1024, 3), 256, 0, stream>>>(WQ, WK, WV, wq, wk, wv);

  // Projections. Qd_t/Kd_t stored (b, seq, o) = one (32768 x 1024) GEMM each;
  // Vd stored (b, o, seq), per-batch z.
  conv_transpose<<<dim3(32, 16, 16), dim3(64, 4), 0, stream>>>(Q, trans);
  gemm_bt<true, true, false, false, false><<<dim3(4, 128, 1), 512, 0, stream>>>(
      trans, wq, qdt, 1024, 1024, 1024, 1024, 0, 0, 0, 1.0f);
  conv_transpose<<<dim3(32, 16, 16), dim3(64, 4), 0, stream>>>(K, trans);
  gemm_bt<true, true, false, false, false><<<dim3(4, 128, 1), 512, 0, stream>>>(
      trans, wk, kdt, 1024, 1024, 1024, 1024, 0, 0, 0, 1.0f);
  conv_transpose<<<dim3(32, 16, 16), dim3(64, 4), 0, stream>>>(V, trans);
  gemm_bt<true, true, false, false, false><<<dim3(8, 4, 16), 512, 0, stream>>>(
      wv, trans, vd, 1024, 1024, 1024, 2048,
      0, (long long)2048 * 1024, (long long)1024 * 2048, 1.0f);

  // Attention per batch-chunk:
  //  S'[t,s] = Kd_t[t,:]·Qd_t[s,:]/32 — compact triangular grid (36 tiles/z),
  //  chunked swizzle -> one batch per XCD (Kd+Qd ws ~8MB, panel-sequential)
  //  row-softmax over s (masked by index), S/P bf16
  //  out[o,t] = sum_s Vd[o,s] P[t,s] — KLIMIT; chunked swizzle gives each XCD
  //  whole batches -> per-XCD KLIMIT work equal; Vd(z)+P(z) L2-resident.
  for (int b0 = 0; b0 < 16; b0 += chunk) {
    const int nb = (16 - b0) < chunk ? (16 - b0) : chunk;
    gemm_bt<true, true, true, false, false><<<dim3(36, 1, nb), 512, 0, stream>>>(
        kdt + (long long)b0 * 2048 * 1024, qdt + (long long)b0 * 2048 * 1024, S,
        1024, 1024, 1024, 2048,
        (long long)2048 * 1024, (long long)2048 * 1024, (long long)2048 * 2048, 0.03125f);
    col_softmax<<<dim3(2048, nb), 256, 0, stream>>>(S, P);
    gemm_bt<false, true, false, true, true><<<dim3(4, 8, nb), 512, 0, stream>>>(
        vd + (long long)b0 * 1024 * 2048, P, out + (long long)b0 * 1024 * 2048,
        2048, 2048, 2048, 2048,
        (long long)1024 * 2048, (long long)2048 * 2048, (long long)1024 * 2048, 1.0f);
  }
}